// Round 6
// baseline (65.391 us; speedup 1.0000x reference)
//
#include <hip/hip_runtime.h>

namespace {
constexpr int H = 2048, W = 2048;
constexpr int CELLS = H * W;
constexpr int PAIRS = CELLS / 2;
constexpr int FRAME_ELEMS = 800 * 800 * 3;    // 1,920,000 floats
constexpr int NEWPOS_OFF = FRAME_ELEMS;
constexpr int ENERGY_OFF = FRAME_ELEMS + CELLS * 2;
constexpr int EN_BLOCKS = 2048, NTHR = 256;   // energy: 8 blocks/CU = 32 waves/CU
constexpr int EN_TOT = EN_BLOCKS * NTHR;
// tiled emit: 8 rows x 256 cols per block -> 256 bands x 8 col-tiles = 2048 blocks
constexpr int TB_ROWS = 8, TB_COLS = 256;
constexpr int EMIT_BLOCKS = (H / TB_ROWS) * (W / TB_COLS);   // 2048
constexpr int FL_ROWS = 4, FL_COLS = 320;     // LDS pixel-flag window (1280 B)
}

// one spring accumulation, reference op order: f += (p - nb) * (-4)
__device__ __forceinline__ void spring(float& f0, float& f1,
                                       float px, float py, float nx, float ny) {
    f0 = __fadd_rn(f0, __fmul_rn(__fsub_rn(px, nx), -4.0f));
    f1 = __fadd_rn(f1, __fmul_rn(__fsub_rn(py, ny), -4.0f));
}

// ---------- k1: frame zero + f64 energy partials (validated R2-R5) ----------
__device__ __forceinline__ void pair_diff(const float4* __restrict__ pos4,
                                          const float2* __restrict__ pos2,
                                          const float4* __restrict__ prev4,
                                          int cp,
                                          float& pa0, float& pa1, float& pb0, float& pb1,
                                          float& da0, float& da1, float& db0, float& db1) {
    const int i = cp >> 10;
    const int jp = (cp & 1023) << 1;
    const float4 s = pos4[cp];
    pa0 = s.x; pa1 = s.y; pb0 = s.z; pb1 = s.w;
    const bool has_u = (i > 0), has_d = (i < H - 1);
    const bool has_l = (jp > 0), has_r = (jp + 2 < W);
    float4 u, d; float2 l, r;
    if (has_u) u = pos4[cp - 1024];
    if (has_d) d = pos4[cp + 1024];
    if (has_l) l = pos2[(i << 11) + jp - 1];
    if (has_r) r = pos2[(i << 11) + jp + 2];

    float fa0 = -9.8f, fa1 = 0.0f, fb0 = -9.8f, fb1 = 0.0f;
    spring(fa0, fa1, s.x, s.y, s.z, s.w);                 // A right = B
    if (has_r) spring(fb0, fb1, s.z, s.w, r.x, r.y);      // B right
    if (has_d) { spring(fa0, fa1, s.x, s.y, d.x, d.y);    // A down
                 spring(fb0, fb1, s.z, s.w, d.z, d.w); }  // B down
    if (has_l) spring(fa0, fa1, s.x, s.y, l.x, l.y);      // A left
    spring(fb0, fb1, s.z, s.w, s.x, s.y);                 // B left = A
    if (has_u) { spring(fa0, fa1, s.x, s.y, u.x, u.y);    // A up
                 spring(fb0, fb1, s.z, s.w, u.z, u.w); }  // B up

    const int jb = jp + 1;
    const bool pinA = ((i == H - 1) && (jp < W / 2) && (jp % 9 == 0)) ||
                      ((i == 0) && (jp % 9 == 0));
    const bool pinB = ((i == H - 1) && (jb < W / 2) && (jb % 9 == 0)) ||
                      ((i == 0) && (jb % 9 == 0));
    if (pinA) { fa0 = 0.0f; fa1 = 0.0f; }
    if (pinB) { fb0 = 0.0f; fb1 = 0.0f; }

    const float4 pv = prev4[cp];
    const float nra0 = __fadd_rn(__fsub_rn(__fmul_rn(2.0f, s.x), pv.x), fa0);
    const float nra1 = __fadd_rn(__fsub_rn(__fmul_rn(2.0f, s.y), pv.y), fa1);
    const float nrb0 = __fadd_rn(__fsub_rn(__fmul_rn(2.0f, s.z), pv.z), fb0);
    const float nrb1 = __fadd_rn(__fsub_rn(__fmul_rn(2.0f, s.w), pv.w), fb1);
    da0 = __fsub_rn(nra0, pa0);
    da1 = __fsub_rn(nra1, pa1);
    db0 = __fsub_rn(nrb0, pb0);
    db1 = __fsub_rn(nrb1, pb1);
}

__global__ __launch_bounds__(NTHR)
void k_energy_zero(const float2* __restrict__ pos2, const float2* __restrict__ prev2,
                   float* __restrict__ out, double* __restrict__ partials) {
    const float4* pos4  = (const float4*)pos2;
    const float4* prev4 = (const float4*)prev2;
    float4* frame4 = (float4*)out;
    const int tid  = threadIdx.x;
    const int gtid = blockIdx.x * NTHR + tid;

    if (gtid < FRAME_ELEMS / 4)
        frame4[gtid] = make_float4(0.f, 0.f, 0.f, 0.f);

    double acc = 0.0;
    #pragma unroll
    for (int it = 0; it < PAIRS / EN_TOT; ++it) {
        const int cp = it * EN_TOT + gtid;
        float pa0, pa1, pb0, pb1, da0, da1, db0, db1;
        pair_diff(pos4, pos2, prev4, cp, pa0, pa1, pb0, pb1, da0, da1, db0, db1);
        const float sA = __fadd_rn(__fmul_rn(da0, da0), __fmul_rn(da1, da1));
        const float vA = __fsqrt_rn(sA);
        acc += (double)__fmul_rn(vA, vA);
        const float sB = __fadd_rn(__fmul_rn(db0, db0), __fmul_rn(db1, db1));
        const float vB = __fsqrt_rn(sB);
        acc += (double)__fmul_rn(vB, vB);
    }
    __shared__ double sm[NTHR];
    sm[tid] = acc;
    __syncthreads();
    for (int s = NTHR / 2; s > 0; s >>= 1) {
        if (tid < s) sm[tid] += sm[tid + s];
        __syncthreads();
    }
    if (tid == 0) partials[blockIdx.x] = sm[0];
}

// ---------- k2: tiny finalize (validated) ----------
__global__ void k_finalize(const double* __restrict__ partials,
                           const float* __restrict__ el_in,
                           float* __restrict__ scale_out,
                           float* __restrict__ out_energy) {
    __shared__ double sm[256];
    const int tid = threadIdx.x;
    double acc = 0.0;
    #pragma unroll
    for (int k = 0; k < EN_BLOCKS / 256; ++k)
        acc += partials[k * 256 + tid];
    sm[tid] = acc;
    __syncthreads();
    for (int s = 128; s > 0; s >>= 1) {
        if (tid < s) sm[tid] += sm[tid + s];
        __syncthreads();
    }
    if (tid == 0) {
        const float energy = (float)sm[0];
        const float el = el_in[0];
        float en = __fmul_rn(fminf(energy, el), 0.99997f);
        en = __fadd_rn(__fmul_rn(en, 0.8f), __fmul_rn(energy, 0.2f));
        scale_out[0] = __fdiv_rn(en, __fadd_rn(energy, 1e-6f));
        out_energy[0] = __fadd_rn(__fmul_rn(el, 0.997f), __fmul_rn(en, 0.003f));
    }
}

// ---------- k3: tiled emit — per-block LDS pixel dedup kills the global
// scatter (1.6M cross-XCD 4B stores -> ~300K block-local stores) ----------
__global__ __launch_bounds__(NTHR)
void k_emit(const float2* __restrict__ pos2, const float2* __restrict__ prev2,
            const float* __restrict__ scale_p, float* __restrict__ out) {
    float2* newpos2 = (float2*)(out + NEWPOS_OFF);
    const int tid  = threadIdx.x;
    const int band = blockIdx.x >> 3;            // 0..255 (8 rows each)
    const int ct   = blockIdx.x & 7;             // col tile 0..7
    const int i0   = band * TB_ROWS;
    const int j    = ct * TB_COLS + tid;
    const float scale = scale_p[0];

    __shared__ unsigned char flags[FL_ROWS * FL_COLS];
    __shared__ int s_minx, s_maxx, s_miny, s_maxy;
    for (int k = tid; k < FL_ROWS * FL_COLS; k += NTHR) flags[k] = 0;
    if (tid == 0) { s_minx = 0x7fffffff; s_maxx = -1; s_miny = 0x7fffffff; s_maxy = -1; }

    int my_px[TB_ROWS], my_py[TB_ROWS];
    int lminx = 0x7fffffff, lmaxx = -1, lminy = 0x7fffffff, lmaxy = -1;

    // rolling rows: rm = row i-1, rc = row i, rp = row i+1
    float2 rm, rc, rp;
    if (i0 > 0) rm = pos2[(i0 - 1) * W + j];
    rc = pos2[i0 * W + j];

    #pragma unroll
    for (int r = 0; r < TB_ROWS; ++r) {
        const int i = i0 + r;
        const bool has_d = (i < H - 1);
        if (has_d) rp = pos2[(i + 1) * W + j];

        float f0 = -9.8f, f1 = 0.0f;
        // DIRS order: right, down, left, up — identical rounding chain to validated path
        if (j < W - 1) { float2 nb = pos2[i * W + j + 1]; spring(f0, f1, rc.x, rc.y, nb.x, nb.y); }
        if (has_d)     { spring(f0, f1, rc.x, rc.y, rp.x, rp.y); }
        if (j > 0)     { float2 nb = pos2[i * W + j - 1]; spring(f0, f1, rc.x, rc.y, nb.x, nb.y); }
        if (i > 0)     { spring(f0, f1, rc.x, rc.y, rm.x, rm.y); }
        const bool pin = ((i == H - 1) && (j < W / 2) && (j % 9 == 0)) ||
                         ((i == 0) && (j % 9 == 0));
        if (pin) { f0 = 0.0f; f1 = 0.0f; }

        const float2 pv = prev2[i * W + j];
        const float nr0 = __fadd_rn(__fsub_rn(__fmul_rn(2.0f, rc.x), pv.x), f0);
        const float nr1 = __fadd_rn(__fsub_rn(__fmul_rn(2.0f, rc.y), pv.y), f1);
        const float d0 = __fsub_rn(nr0, rc.x);
        const float d1 = __fsub_rn(nr1, rc.y);
        const float sq = __fadd_rn(__fmul_rn(d0, d0), __fmul_rn(d1, d1));
        const float v  = __fsqrt_rn(sq);
        const float vel = __fmul_rn(v, scale);
        const float den = fmaxf(v, 1e-12f);
        const float n0 = __fadd_rn(rc.x, __fmul_rn(__fdiv_rn(d0, den), vel));
        const float n1 = __fadd_rn(rc.y, __fmul_rn(__fdiv_rn(d1, den), vel));
        newpos2[i * W + j] = make_float2(n0, n1);

        const float x = __fadd_rn(__fmul_rn(__fmul_rn(n1, 4.8828125e-4f), 784.0f), 10.0f);
        const float y = __fadd_rn(__fmul_rn(__fmul_rn(n0, 4.8828125e-4f), 104.0f), 690.0f);
        const int xi = (int)fminf(fmaxf(x, 0.0f), 803.0f);
        const int yi = (int)fminf(fmaxf(y, 0.0f), 803.0f);
        const int px = xi - 2, py = yi - 2;       // crop [2:802,2:802]
        const bool ok = ((unsigned)px < 800u) && ((unsigned)py < 800u);
        my_px[r] = ok ? px : -1;
        my_py[r] = ok ? py : 0;
        if (ok) {
            lminx = min(lminx, px); lmaxx = max(lmaxx, px);
            lminy = min(lminy, py); lmaxy = max(lmaxy, py);
        }
        rm = rc; rc = rp;
    }

    __syncthreads();                              // s_* init + flags zero visible
    if (lmaxx >= 0) {
        atomicMin(&s_minx, lminx); atomicMax(&s_maxx, lmaxx);
        atomicMin(&s_miny, lminy); atomicMax(&s_maxy, lmaxy);
    }
    __syncthreads();

    const int minx = s_minx, miny = s_miny;
    const bool fits = (s_maxx >= 0) &&
                      (s_maxx - minx < FL_COLS) && (s_maxy - miny < FL_ROWS);
    if (fits) {
        #pragma unroll
        for (int r = 0; r < TB_ROWS; ++r)
            if (my_px[r] >= 0)
                flags[(my_py[r] - miny) * FL_COLS + (my_px[r] - minx)] = 1;
    } else {
        #pragma unroll
        for (int r = 0; r < TB_ROWS; ++r)         // rare fallback: direct stores
            if (my_px[r] >= 0)
                out[(my_py[r] * 800 + my_px[r]) * 3 + 1] = 255.0f;
    }
    __syncthreads();
    if (fits) {
        const int rows = s_maxy - miny + 1, cols = s_maxx - minx + 1;
        for (int ry = 0; ry < rows; ++ry) {
            const int base = (miny + ry) * 800 + minx;
            for (int k = tid; k < cols; k += NTHR)
                if (flags[ry * FL_COLS + k])
                    out[(base + k) * 3 + 1] = 255.0f;   // idempotent across blocks
        }
    }
}

extern "C" void kernel_launch(void* const* d_in, const int* in_sizes, int n_in,
                              void* d_out, int out_size, void* d_ws, size_t ws_size,
                              hipStream_t stream) {
    const float2* pos  = (const float2*)d_in[0];
    const float2* prev = (const float2*)d_in[1];
    const float*  el   = (const float*)d_in[2];
    float* out = (float*)d_out;
    double* partials = (double*)d_ws;
    float*  scale_p  = (float*)((char*)d_ws + EN_BLOCKS * sizeof(double));

    hipLaunchKernelGGL(k_energy_zero, dim3(EN_BLOCKS), dim3(NTHR), 0, stream,
                       pos, prev, out, partials);
    hipLaunchKernelGGL(k_finalize, dim3(1), dim3(256), 0, stream,
                       partials, el, scale_p, out + ENERGY_OFF);
    hipLaunchKernelGGL(k_emit, dim3(EMIT_BLOCKS), dim3(NTHR), 0, stream,
                       pos, prev, scale_p, out);
}

// Round 7
// 54.365 us; speedup vs baseline: 1.2028x; 1.2028x over previous
//
#include <hip/hip_runtime.h>

namespace {
constexpr int H = 2048, W = 2048;
constexpr int CELLS = H * W;
constexpr int PAIRS = CELLS / 2;
constexpr int FRAME_ELEMS = 800 * 800 * 3;    // 1,920,000 floats
constexpr int NEWPOS_OFF = FRAME_ELEMS;
constexpr int ENERGY_OFF = FRAME_ELEMS + CELLS * 2;
constexpr int EN_BLOCKS = 2048, NTHR = 256;   // 8 blocks/CU = 32 waves/CU resident
constexpr int EN_TOT = EN_BLOCKS * NTHR;
constexpr int EMIT_BLOCKS = PAIRS / NTHR;     // 8192 blocks, 1 pair/thread
constexpr int FR_ROWS = 16;                   // k_frame: rows per thread (vertical dedup)
constexpr int FR_BLOCKS = (H / FR_ROWS) * (W / NTHR);   // 128 strips * 8 tiles = 1024
}

// one spring accumulation, reference op order: f += (p - nb) * (-4)
__device__ __forceinline__ void spring(float& f0, float& f1,
                                       float px, float py, float nx, float ny) {
    f0 = __fadd_rn(f0, __fmul_rn(__fsub_rn(px, nx), -4.0f));
    f1 = __fadd_rn(f1, __fmul_rn(__fsub_rn(py, ny), -4.0f));
}

// pos + diff for cell pair (i,jp),(i,jp+1). Exact reference f32 op order
// (DIRS per cell: right, down, left, up). Validated R2-R6: absmax 0.0078.
__device__ __forceinline__ void pair_diff(const float4* __restrict__ pos4,
                                          const float2* __restrict__ pos2,
                                          const float4* __restrict__ prev4,
                                          int cp,
                                          float& pa0, float& pa1, float& pb0, float& pb1,
                                          float& da0, float& da1, float& db0, float& db1) {
    const int i = cp >> 10;
    const int jp = (cp & 1023) << 1;
    const float4 s = pos4[cp];
    pa0 = s.x; pa1 = s.y; pb0 = s.z; pb1 = s.w;
    const bool has_u = (i > 0), has_d = (i < H - 1);
    const bool has_l = (jp > 0), has_r = (jp + 2 < W);
    float4 u, d; float2 l, r;
    if (has_u) u = pos4[cp - 1024];
    if (has_d) d = pos4[cp + 1024];
    if (has_l) l = pos2[(i << 11) + jp - 1];
    if (has_r) r = pos2[(i << 11) + jp + 2];

    float fa0 = -9.8f, fa1 = 0.0f, fb0 = -9.8f, fb1 = 0.0f;
    spring(fa0, fa1, s.x, s.y, s.z, s.w);                 // A right = B
    if (has_r) spring(fb0, fb1, s.z, s.w, r.x, r.y);      // B right
    if (has_d) { spring(fa0, fa1, s.x, s.y, d.x, d.y);    // A down
                 spring(fb0, fb1, s.z, s.w, d.z, d.w); }  // B down
    if (has_l) spring(fa0, fa1, s.x, s.y, l.x, l.y);      // A left
    spring(fb0, fb1, s.z, s.w, s.x, s.y);                 // B left = A
    if (has_u) { spring(fa0, fa1, s.x, s.y, u.x, u.y);    // A up
                 spring(fb0, fb1, s.z, s.w, u.z, u.w); }  // B up

    const int jb = jp + 1;
    const bool pinA = ((i == H - 1) && (jp < W / 2) && (jp % 9 == 0)) ||
                      ((i == 0) && (jp % 9 == 0));
    const bool pinB = ((i == H - 1) && (jb < W / 2) && (jb % 9 == 0)) ||
                      ((i == 0) && (jb % 9 == 0));
    if (pinA) { fa0 = 0.0f; fa1 = 0.0f; }
    if (pinB) { fb0 = 0.0f; fb1 = 0.0f; }

    const float4 pv = prev4[cp];
    const float nra0 = __fadd_rn(__fsub_rn(__fmul_rn(2.0f, s.x), pv.x), fa0);
    const float nra1 = __fadd_rn(__fsub_rn(__fmul_rn(2.0f, s.y), pv.y), fa1);
    const float nrb0 = __fadd_rn(__fsub_rn(__fmul_rn(2.0f, s.z), pv.z), fb0);
    const float nrb1 = __fadd_rn(__fsub_rn(__fmul_rn(2.0f, s.w), pv.w), fb1);
    da0 = __fsub_rn(nra0, pa0);
    da1 = __fsub_rn(nra1, pa1);
    db0 = __fsub_rn(nrb0, pb0);
    db1 = __fsub_rn(nrb1, pb1);
}

// ---------- k1: frame zero + f64 energy partials (validated) ----------
__global__ __launch_bounds__(NTHR)
void k_energy_zero(const float2* __restrict__ pos2, const float2* __restrict__ prev2,
                   float* __restrict__ out, double* __restrict__ partials) {
    const float4* pos4  = (const float4*)pos2;
    const float4* prev4 = (const float4*)prev2;
    float4* frame4 = (float4*)out;
    const int tid  = threadIdx.x;
    const int gtid = blockIdx.x * NTHR + tid;

    if (gtid < FRAME_ELEMS / 4)
        frame4[gtid] = make_float4(0.f, 0.f, 0.f, 0.f);

    double acc = 0.0;
    #pragma unroll
    for (int it = 0; it < PAIRS / EN_TOT; ++it) {
        const int cp = it * EN_TOT + gtid;
        float pa0, pa1, pb0, pb1, da0, da1, db0, db1;
        pair_diff(pos4, pos2, prev4, cp, pa0, pa1, pb0, pb1, da0, da1, db0, db1);
        const float sA = __fadd_rn(__fmul_rn(da0, da0), __fmul_rn(da1, da1));
        const float vA = __fsqrt_rn(sA);
        acc += (double)__fmul_rn(vA, vA);
        const float sB = __fadd_rn(__fmul_rn(db0, db0), __fmul_rn(db1, db1));
        const float vB = __fsqrt_rn(sB);
        acc += (double)__fmul_rn(vB, vB);
    }
    __shared__ double sm[NTHR];
    sm[tid] = acc;
    __syncthreads();
    for (int s = NTHR / 2; s > 0; s >>= 1) {
        if (tid < s) sm[tid] += sm[tid + s];
        __syncthreads();
    }
    if (tid == 0) partials[blockIdx.x] = sm[0];
}

// ---------- k2: tiny finalize (validated) ----------
__global__ void k_finalize(const double* __restrict__ partials,
                           const float* __restrict__ el_in,
                           float* __restrict__ scale_out,
                           float* __restrict__ out_energy) {
    __shared__ double sm[256];
    const int tid = threadIdx.x;
    double acc = 0.0;
    #pragma unroll
    for (int k = 0; k < EN_BLOCKS / 256; ++k)
        acc += partials[k * 256 + tid];
    sm[tid] = acc;
    __syncthreads();
    for (int s = 128; s > 0; s >>= 1) {
        if (tid < s) sm[tid] += sm[tid + s];
        __syncthreads();
    }
    if (tid == 0) {
        const float energy = (float)sm[0];
        const float el = el_in[0];
        float en = __fmul_rn(fminf(energy, el), 0.99997f);
        en = __fadd_rn(__fmul_rn(en, 0.8f), __fmul_rn(energy, 0.2f));
        scale_out[0] = __fdiv_rn(en, __fadd_rn(energy, 1e-6f));
        out_energy[0] = __fadd_rn(__fmul_rn(el, 0.997f), __fmul_rn(en, 0.003f));
    }
}

// ---------- k3: pure streaming newpos — NO scatter (scatter ablation) ----------
__global__ __launch_bounds__(NTHR)
void k_emit_pos(const float2* __restrict__ pos2, const float2* __restrict__ prev2,
                const float* __restrict__ scale_p, float* __restrict__ out) {
    const float4* pos4  = (const float4*)pos2;
    const float4* prev4 = (const float4*)prev2;
    float4* newpos4 = (float4*)(out + NEWPOS_OFF);
    const int cp = blockIdx.x * NTHR + threadIdx.x;
    const float scale = scale_p[0];
    float pa0, pa1, pb0, pb1, da0, da1, db0, db1;
    pair_diff(pos4, pos2, prev4, cp, pa0, pa1, pb0, pb1, da0, da1, db0, db1);

    const float sA = __fadd_rn(__fmul_rn(da0, da0), __fmul_rn(da1, da1));
    const float vA = __fsqrt_rn(sA);
    const float velA = __fmul_rn(vA, scale);
    const float denA = fmaxf(vA, 1e-12f);
    const float na0 = __fadd_rn(pa0, __fmul_rn(__fdiv_rn(da0, denA), velA));
    const float na1 = __fadd_rn(pa1, __fmul_rn(__fdiv_rn(da1, denA), velA));

    const float sB = __fadd_rn(__fmul_rn(db0, db0), __fmul_rn(db1, db1));
    const float vB = __fsqrt_rn(sB);
    const float velB = __fmul_rn(vB, scale);
    const float denB = fmaxf(vB, 1e-12f);
    const float nb0 = __fadd_rn(pb0, __fmul_rn(__fdiv_rn(db0, denB), velB));
    const float nb1 = __fadd_rn(pb1, __fmul_rn(__fdiv_rn(db1, denB), velB));

    newpos4[cp] = make_float4(na0, na1, nb0, nb1);
}

// ---------- k4: rasterize from stored newpos (cache-hot), vertical+horizontal
// dedup cuts ~1.6M scattered stores to ~100-200K. Bit-exact: pixels computed
// from the same rounded f32 newpos values the reference uses. ----------
__global__ __launch_bounds__(NTHR)
void k_frame(const float* __restrict__ newpos_f, float* __restrict__ out) {
    const float2* np2 = (const float2*)newpos_f;
    const int tid   = threadIdx.x;
    const int strip = blockIdx.x >> 3;            // 0..127 (16 rows each)
    const int ct    = blockIdx.x & 7;             // col tile 0..7
    const int j     = ct * NTHR + tid;
    const int i0    = strip * FR_ROWS;

    int prev_pix = -1;
    #pragma unroll
    for (int r = 0; r < FR_ROWS; ++r) {
        const float2 n = np2[(i0 + r) * W + j];   // coalesced 512B/wave
        const float x = __fadd_rn(__fmul_rn(__fmul_rn(n.y, 4.8828125e-4f), 784.0f), 10.0f);
        const float y = __fadd_rn(__fmul_rn(__fmul_rn(n.x, 4.8828125e-4f), 104.0f), 690.0f);
        const int xi = (int)fminf(fmaxf(x, 0.0f), 803.0f);
        const int yi = (int)fminf(fmaxf(y, 0.0f), 803.0f);
        const int px = xi - 2, py = yi - 2;       // crop [2:802,2:802]
        int pix = -1;
        if ((unsigned)px < 800u && (unsigned)py < 800u) pix = py * 800 + px;
        // dedup: vertical (same thread, prev row) + horizontal (left lane, same row).
        // Lossless by induction: every skipped pix is seen (and eventually stored)
        // at (r-1, lane) or (r, lane-1); stores are idempotent (constant 255).
        const int left = __shfl_up(pix, 1);
        const bool dup_h = ((tid & 63) > 0) && (left == pix);
        if (pix >= 0 && pix != prev_pix && !dup_h)
            out[pix * 3 + 1] = 255.0f;
        prev_pix = pix;
    }
}

extern "C" void kernel_launch(void* const* d_in, const int* in_sizes, int n_in,
                              void* d_out, int out_size, void* d_ws, size_t ws_size,
                              hipStream_t stream) {
    const float2* pos  = (const float2*)d_in[0];
    const float2* prev = (const float2*)d_in[1];
    const float*  el   = (const float*)d_in[2];
    float* out = (float*)d_out;
    double* partials = (double*)d_ws;
    float*  scale_p  = (float*)((char*)d_ws + EN_BLOCKS * sizeof(double));

    hipLaunchKernelGGL(k_energy_zero, dim3(EN_BLOCKS), dim3(NTHR), 0, stream,
                       pos, prev, out, partials);
    hipLaunchKernelGGL(k_finalize, dim3(1), dim3(256), 0, stream,
                       partials, el, scale_p, out + ENERGY_OFF);
    hipLaunchKernelGGL(k_emit_pos, dim3(EMIT_BLOCKS), dim3(NTHR), 0, stream,
                       pos, prev, scale_p, out);
    hipLaunchKernelGGL(k_frame, dim3(FR_BLOCKS), dim3(NTHR), 0, stream,
                       out + NEWPOS_OFF, out);
}

// Round 8
// 41.467 us; speedup vs baseline: 1.5769x; 1.3110x over previous
//
#include <hip/hip_runtime.h>

namespace {
constexpr int H = 2048, W = 2048;
constexpr int PW = W / 2;                     // pair-columns per row = 1024
constexpr int CELLS = H * W;
constexpr int FRAME_ELEMS = 800 * 800 * 3;    // 1,920,000 floats
constexpr int NEWPOS_OFF = FRAME_ELEMS;
constexpr int ENERGY_OFF = FRAME_ELEMS + CELLS * 2;
constexpr int NTHR = 256;
constexpr int NR = 8;                         // rows per band (halo overhead 1.25x)
constexpr int BANDS = H / NR;                 // 256
constexpr int CTILES = PW / NTHR;             // 4 col-tiles of 256 pair-cols
constexpr int NBLK = BANDS * CTILES;          // 1024 blocks
}

// one spring accumulation, reference op order: f += (p - nb) * (-4)
__device__ __forceinline__ void spring(float& f0, float& f1,
                                       float px, float py, float nx, float ny) {
    f0 = __fadd_rn(f0, __fmul_rn(__fsub_rn(px, nx), -4.0f));
    f1 = __fadd_rn(f1, __fmul_rn(__fsub_rn(py, ny), -4.0f));
}

// diff for the pair (A,B) of one row, given center/up/down float4 rows and
// shfl-provided left/right cells. Exact reference op order (right,down,left,up),
// identical rounding chain to the R2-R7 validated path.
__device__ __forceinline__ void row_diff(float4 c, float4 up, float4 dn,
                                         bool has_u, bool has_d,
                                         float lx, float ly, bool has_l,
                                         float rx, float ry, bool has_r,
                                         float4 pv, int i, int jp,
                                         float& da0, float& da1,
                                         float& db0, float& db1) {
    float fa0 = -9.8f, fa1 = 0.0f, fb0 = -9.8f, fb1 = 0.0f;
    spring(fa0, fa1, c.x, c.y, c.z, c.w);                  // A right = B
    if (has_r) spring(fb0, fb1, c.z, c.w, rx, ry);         // B right
    if (has_d) { spring(fa0, fa1, c.x, c.y, dn.x, dn.y);   // A down
                 spring(fb0, fb1, c.z, c.w, dn.z, dn.w); } // B down
    if (has_l) spring(fa0, fa1, c.x, c.y, lx, ly);         // A left
    spring(fb0, fb1, c.z, c.w, c.x, c.y);                  // B left = A
    if (has_u) { spring(fa0, fa1, c.x, c.y, up.x, up.y);   // A up
                 spring(fb0, fb1, c.z, c.w, up.z, up.w); } // B up

    const int jb = jp + 1;
    const bool pinA = ((i == H - 1) && (jp < W / 2) && (jp % 9 == 0)) ||
                      ((i == 0) && (jp % 9 == 0));
    const bool pinB = ((i == H - 1) && (jb < W / 2) && (jb % 9 == 0)) ||
                      ((i == 0) && (jb % 9 == 0));
    if (pinA) { fa0 = 0.0f; fa1 = 0.0f; }
    if (pinB) { fb0 = 0.0f; fb1 = 0.0f; }

    const float nra0 = __fadd_rn(__fsub_rn(__fmul_rn(2.0f, c.x), pv.x), fa0);
    const float nra1 = __fadd_rn(__fsub_rn(__fmul_rn(2.0f, c.y), pv.y), fa1);
    const float nrb0 = __fadd_rn(__fsub_rn(__fmul_rn(2.0f, c.z), pv.z), fb0);
    const float nrb1 = __fadd_rn(__fsub_rn(__fmul_rn(2.0f, c.w), pv.w), fb1);
    da0 = __fsub_rn(nra0, c.x);
    da1 = __fsub_rn(nra1, c.y);
    db0 = __fsub_rn(nrb0, c.z);
    db1 = __fsub_rn(nrb1, c.w);
}

// Load the band's pos rows once (halo included), fetch l/r via shfl.
// lane 0/63 take a tiny predicated 8B load (wave = 64 consecutive pair-cols).
#define BAND_PROLOGUE                                                          \
    const int tid  = threadIdx.x;                                              \
    const int lane = tid & 63;                                                 \
    const int band = blockIdx.x >> 2;                                          \
    const int ct   = blockIdx.x & 3;                                           \
    const int i0   = band * NR;                                                \
    const int pj   = ct * NTHR + tid;          /* pair col 0..1023 */          \
    const int jp   = pj << 1;                                                  \
    float4 P[NR + 2];                                                          \
    _Pragma("unroll")                                                          \
    for (int r = 0; r < NR + 2; ++r) {                                         \
        const int row = i0 - 1 + r;                                            \
        P[r] = (row >= 0 && row < H) ? pos4[row * PW + pj]                     \
                                     : make_float4(0.f, 0.f, 0.f, 0.f);        \
    }

#define ROW_NEIGHBORS(r)                                                       \
    const int i = i0 + (r);                                                    \
    const float4 c  = P[(r) + 1];                                              \
    const bool has_u = (i > 0), has_d = (i < H - 1);                           \
    const bool has_l = (jp > 0), has_r = (jp + 2 < W);                         \
    float lx = __shfl_up(c.z, 1), ly = __shfl_up(c.w, 1);                      \
    if (lane == 0 && has_l) {                                                  \
        const float2 t = pos2[i * W + jp - 1]; lx = t.x; ly = t.y;             \
    }                                                                          \
    float rx = __shfl_down(c.x, 1), ry = __shfl_down(c.y, 1);                  \
    if (lane == 63 && has_r) {                                                 \
        const float2 t = pos2[i * W + jp + 2]; rx = t.x; ry = t.y;             \
    }                                                                          \
    const float4 pv = prev4[i * PW + pj];

// ---------- k1: frame-zero + band energy partials (read-once stencil) ----------
__global__ __launch_bounds__(NTHR)
void k_energy_band(const float2* __restrict__ pos2, const float2* __restrict__ prev2,
                   float* __restrict__ out, double* __restrict__ partials) {
    const float4* pos4  = (const float4*)pos2;
    const float4* prev4 = (const float4*)prev2;
    float4* frame4 = (float4*)out;
    {   // zero the frame: 1024*256 threads, <=2 float4 each
        const int gtid = blockIdx.x * NTHR + threadIdx.x;
        for (int k = gtid; k < FRAME_ELEMS / 4; k += NBLK * NTHR)
            frame4[k] = make_float4(0.f, 0.f, 0.f, 0.f);
    }
    BAND_PROLOGUE

    double acc = 0.0;
    #pragma unroll
    for (int r = 0; r < NR; ++r) {
        ROW_NEIGHBORS(r)
        float da0, da1, db0, db1;
        row_diff(c, P[r], P[r + 2], has_u, has_d, lx, ly, has_l, rx, ry, has_r,
                 pv, i, jp, da0, da1, db0, db1);
        const float sA = __fadd_rn(__fmul_rn(da0, da0), __fmul_rn(da1, da1));
        const float vA = __fsqrt_rn(sA);
        acc += (double)__fmul_rn(vA, vA);
        const float sB = __fadd_rn(__fmul_rn(db0, db0), __fmul_rn(db1, db1));
        const float vB = __fsqrt_rn(sB);
        acc += (double)__fmul_rn(vB, vB);
    }
    __shared__ double sm[NTHR];
    sm[tid] = acc;
    __syncthreads();
    for (int s = NTHR / 2; s > 0; s >>= 1) {
        if (tid < s) sm[tid] += sm[tid + s];
        __syncthreads();
    }
    if (tid == 0) partials[blockIdx.x] = sm[0];
}

// ---------- k2: tiny finalize (validated; fixed-order f64) ----------
__global__ void k_finalize(const double* __restrict__ partials,
                           const float* __restrict__ el_in,
                           float* __restrict__ scale_out,
                           float* __restrict__ out_energy) {
    __shared__ double sm[256];
    const int tid = threadIdx.x;
    double acc = 0.0;
    #pragma unroll
    for (int k = 0; k < NBLK / 256; ++k)
        acc += partials[k * 256 + tid];
    sm[tid] = acc;
    __syncthreads();
    for (int s = 128; s > 0; s >>= 1) {
        if (tid < s) sm[tid] += sm[tid + s];
        __syncthreads();
    }
    if (tid == 0) {
        const float energy = (float)sm[0];
        const float el = el_in[0];
        float en = __fmul_rn(fminf(energy, el), 0.99997f);             // min * DECAY
        en = __fadd_rn(__fmul_rn(en, 0.8f), __fmul_rn(energy, 0.2f)); // pp blend
        scale_out[0] = __fdiv_rn(en, __fadd_rn(energy, 1e-6f));
        out_energy[0] = __fadd_rn(__fmul_rn(el, 0.997f), __fmul_rn(en, 0.003f));
    }
}

// ---------- k3: band emit — read-once stencil, newpos + raster with
// vertical (per-thread rolling) + horizontal (shfl) pixel dedup ----------
__global__ __launch_bounds__(NTHR)
void k_emit_band(const float2* __restrict__ pos2, const float2* __restrict__ prev2,
                 const float* __restrict__ scale_p, float* __restrict__ out) {
    const float4* pos4  = (const float4*)pos2;
    const float4* prev4 = (const float4*)prev2;
    float4* newpos4 = (float4*)(out + NEWPOS_OFF);
    const float scale = scale_p[0];
    BAND_PROLOGUE

    int prevA = -1, prevB = -1;               // vertical dedup state
    #pragma unroll
    for (int r = 0; r < NR; ++r) {
        ROW_NEIGHBORS(r)
        float da0, da1, db0, db1;
        row_diff(c, P[r], P[r + 2], has_u, has_d, lx, ly, has_l, rx, ry, has_r,
                 pv, i, jp, da0, da1, db0, db1);

        const float sA = __fadd_rn(__fmul_rn(da0, da0), __fmul_rn(da1, da1));
        const float vA = __fsqrt_rn(sA);
        const float velA = __fmul_rn(vA, scale);
        const float denA = fmaxf(vA, 1e-12f);
        const float na0 = __fadd_rn(c.x, __fmul_rn(__fdiv_rn(da0, denA), velA));
        const float na1 = __fadd_rn(c.y, __fmul_rn(__fdiv_rn(da1, denA), velA));

        const float sB = __fadd_rn(__fmul_rn(db0, db0), __fmul_rn(db1, db1));
        const float vB = __fsqrt_rn(sB);
        const float velB = __fmul_rn(vB, scale);
        const float denB = fmaxf(vB, 1e-12f);
        const float nb0 = __fadd_rn(c.z, __fmul_rn(__fdiv_rn(db0, denB), velB));
        const float nb1 = __fadd_rn(c.w, __fmul_rn(__fdiv_rn(db1, denB), velB));

        newpos4[i * PW + pj] = make_float4(na0, na1, nb0, nb1);

        // pixel indices (crop [2:802,2:802]); /2048 == *2^-11 exact
        const float xA = __fadd_rn(__fmul_rn(__fmul_rn(na1, 4.8828125e-4f), 784.0f), 10.0f);
        const float yA = __fadd_rn(__fmul_rn(__fmul_rn(na0, 4.8828125e-4f), 104.0f), 690.0f);
        const int pxA = (int)fminf(fmaxf(xA, 0.0f), 803.0f) - 2;
        const int pyA = (int)fminf(fmaxf(yA, 0.0f), 803.0f) - 2;
        int pixA = -1;
        if ((unsigned)pxA < 800u && (unsigned)pyA < 800u) pixA = pyA * 800 + pxA;

        const float xB = __fadd_rn(__fmul_rn(__fmul_rn(nb1, 4.8828125e-4f), 784.0f), 10.0f);
        const float yB = __fadd_rn(__fmul_rn(__fmul_rn(nb0, 4.8828125e-4f), 104.0f), 690.0f);
        const int pxB = (int)fminf(fmaxf(xB, 0.0f), 803.0f) - 2;
        const int pyB = (int)fminf(fmaxf(yB, 0.0f), 803.0f) - 2;
        int pixB = -1;
        if ((unsigned)pxB < 800u && (unsigned)pyB < 800u) pixB = pyB * 800 + pxB;

        // dedup: vertical (same thread, row i-1) + horizontal (left lane B, own A).
        // Lossless: every skipped pixel's duplicate occurrence is earlier in the
        // (row, chain) DAG and stores are idempotent (constant 255).
        const int leftB = __shfl_up(pixB, 1);
        const bool dupA = (pixA == prevA) || (lane > 0 && pixA == leftB);
        const bool dupB = (pixB == prevB) || (pixB == pixA);
        if (pixA >= 0 && !dupA) out[pixA * 3 + 1] = 255.0f;
        if (pixB >= 0 && !dupB) out[pixB * 3 + 1] = 255.0f;
        prevA = pixA; prevB = pixB;
    }
}

extern "C" void kernel_launch(void* const* d_in, const int* in_sizes, int n_in,
                              void* d_out, int out_size, void* d_ws, size_t ws_size,
                              hipStream_t stream) {
    const float2* pos  = (const float2*)d_in[0];
    const float2* prev = (const float2*)d_in[1];
    const float*  el   = (const float*)d_in[2];
    float* out = (float*)d_out;
    double* partials = (double*)d_ws;
    float*  scale_p  = (float*)((char*)d_ws + NBLK * sizeof(double));

    hipLaunchKernelGGL(k_energy_band, dim3(NBLK), dim3(NTHR), 0, stream,
                       pos, prev, out, partials);
    hipLaunchKernelGGL(k_finalize, dim3(1), dim3(256), 0, stream,
                       partials, el, scale_p, out + ENERGY_OFF);
    hipLaunchKernelGGL(k_emit_band, dim3(NBLK), dim3(NTHR), 0, stream,
                       pos, prev, scale_p, out);
}

// Round 9
// 39.162 us; speedup vs baseline: 1.6697x; 1.0588x over previous
//
#include <hip/hip_runtime.h>

namespace {
constexpr int H = 2048, W = 2048;
constexpr int PW = W / 2;                     // pair-columns per row
constexpr int CELLS = H * W;
constexpr int FRAME_ELEMS = 800 * 800 * 3;
constexpr int NEWPOS_OFF = FRAME_ELEMS;
constexpr int ENERGY_OFF = FRAME_ELEMS + CELLS * 2;
constexpr int NTHR = 256;
constexpr int NR = 8;                         // rows per band; halo 10/8 = 1.25x
constexpr int BANDS = H / NR;                 // 256
constexpr int CTILES = PW / NTHR;             // 4
constexpr int NBLK = BANDS * CTILES;          // 1024 blocks, 4/CU resident
}

__device__ __forceinline__ void spring(float& f0, float& f1,
                                       float px, float py, float nx, float ny) {
    f0 = __fadd_rn(f0, __fmul_rn(__fsub_rn(px, nx), -4.0f));
    f1 = __fadd_rn(f1, __fmul_rn(__fsub_rn(py, ny), -4.0f));
}

// diff for pair (A,B): exact reference force chain (right,down,left,up + pins).
// maybe_pin is uniform & false for 2046/2048 rows -> pin VALU skipped entirely.
__device__ __forceinline__ void row_diff(float4 c, float4 up, float4 dn,
                                         bool has_u, bool has_d,
                                         float lx, float ly, bool has_l,
                                         float rx, float ry, bool has_r,
                                         float4 pv, bool maybe_pin, int i, int jp,
                                         float& da0, float& da1,
                                         float& db0, float& db1) {
    float fa0 = -9.8f, fa1 = 0.0f, fb0 = -9.8f, fb1 = 0.0f;
    spring(fa0, fa1, c.x, c.y, c.z, c.w);                  // A right = B
    if (has_r) spring(fb0, fb1, c.z, c.w, rx, ry);         // B right
    if (has_d) { spring(fa0, fa1, c.x, c.y, dn.x, dn.y);   // A down
                 spring(fb0, fb1, c.z, c.w, dn.z, dn.w); } // B down
    if (has_l) spring(fa0, fa1, c.x, c.y, lx, ly);         // A left
    spring(fb0, fb1, c.z, c.w, c.x, c.y);                  // B left = A
    if (has_u) { spring(fa0, fa1, c.x, c.y, up.x, up.y);   // A up
                 spring(fb0, fb1, c.z, c.w, up.z, up.w); } // B up
    if (maybe_pin) {
        const int jb = jp + 1;
        const bool pinA = ((i == H - 1) && (jp < W / 2) && (jp % 9 == 0)) ||
                          ((i == 0) && (jp % 9 == 0));
        const bool pinB = ((i == H - 1) && (jb < W / 2) && (jb % 9 == 0)) ||
                          ((i == 0) && (jb % 9 == 0));
        if (pinA) { fa0 = 0.0f; fa1 = 0.0f; }
        if (pinB) { fb0 = 0.0f; fb1 = 0.0f; }
    }
    da0 = __fsub_rn(__fadd_rn(__fsub_rn(__fmul_rn(2.0f, c.x), pv.x), fa0), c.x);
    da1 = __fsub_rn(__fadd_rn(__fsub_rn(__fmul_rn(2.0f, c.y), pv.y), fa1), c.y);
    db0 = __fsub_rn(__fadd_rn(__fsub_rn(__fmul_rn(2.0f, c.z), pv.z), fb0), c.z);
    db1 = __fsub_rn(__fadd_rn(__fsub_rn(__fmul_rn(2.0f, c.w), pv.w), fb1), c.w);
}

#define BAND_PROLOGUE                                                          \
    const int tid  = threadIdx.x;                                              \
    const int lane = tid & 63;                                                 \
    const int band = blockIdx.x >> 2;                                          \
    const int ct   = blockIdx.x & 3;                                           \
    const int i0   = band * NR;                                                \
    const int pj   = ct * NTHR + tid;                                          \
    const int jp   = pj << 1;                                                  \
    float4 P[NR + 2];                                                          \
    _Pragma("unroll")                                                          \
    for (int r = 0; r < NR + 2; ++r) {                                         \
        const int row = i0 - 1 + r;                                            \
        P[r] = (row >= 0 && row < H) ? pos4[row * PW + pj]                     \
                                     : make_float4(0.f, 0.f, 0.f, 0.f);        \
    }

#define ROW_NEIGHBORS(r)                                                       \
    const int i = i0 + (r);                                                    \
    const float4 c = P[(r) + 1];                                               \
    const bool has_u = !((r) == 0 && band == 0);                               \
    const bool has_d = !((r) == NR - 1 && band == BANDS - 1);                  \
    const bool has_l = (jp > 0), has_r = (jp + 2 < W);                         \
    float lx = __shfl_up(c.z, 1), ly = __shfl_up(c.w, 1);                      \
    if (lane == 0 && has_l) {                                                  \
        const float2 t = pos2[i * W + jp - 1]; lx = t.x; ly = t.y;             \
    }                                                                          \
    float rx = __shfl_down(c.x, 1), ry = __shfl_down(c.y, 1);                  \
    if (lane == 63 && has_r) {                                                 \
        const float2 t = pos2[i * W + jp + 2]; rx = t.x; ry = t.y;             \
    }                                                                          \
    const float4 pv = prev4[i * PW + pj];                                      \
    const bool maybe_pin = ((r) == 0 && band == 0) ||                          \
                           ((r) == NR - 1 && band == BANDS - 1);

// ---------- k1: frame zero + band energy partials ----------
__global__ __launch_bounds__(NTHR)
void k_energy(const float2* __restrict__ pos2, const float2* __restrict__ prev2,
              float* __restrict__ out, double* __restrict__ partials) {
    const float4* pos4  = (const float4*)pos2;
    const float4* prev4 = (const float4*)prev2;
    float4* frame4 = (float4*)out;
    {
        const int gtid = blockIdx.x * NTHR + threadIdx.x;
        for (int k = gtid; k < FRAME_ELEMS / 4; k += NBLK * NTHR)
            frame4[k] = make_float4(0.f, 0.f, 0.f, 0.f);
    }
    BAND_PROLOGUE

    double acc = 0.0;
    #pragma unroll
    for (int r = 0; r < NR; ++r) {
        ROW_NEIGHBORS(r)
        float da0, da1, db0, db1;
        row_diff(c, P[r], P[r + 2], has_u, has_d, lx, ly, has_l, rx, ry, has_r,
                 pv, maybe_pin, i, jp, da0, da1, db0, db1);
        // sum vnorm^2 directly (skip sqrt->square round-trip; ~1e-7 rel shift,
        // threshold is ~2% global -> safe)
        acc += (double)__fadd_rn(__fmul_rn(da0, da0), __fmul_rn(da1, da1));
        acc += (double)__fadd_rn(__fmul_rn(db0, db0), __fmul_rn(db1, db1));
    }
    __shared__ double sm[NTHR];
    sm[tid] = acc;
    __syncthreads();
    for (int s = NTHR / 2; s > 0; s >>= 1) {
        if (tid < s) sm[tid] += sm[tid + s];
        __syncthreads();
    }
    if (tid == 0) partials[blockIdx.x] = sm[0];
}

// ---------- k2: wave-redundant reduce (no barriers) + lean band emit ----------
__global__ __launch_bounds__(NTHR)
void k_emit(const float2* __restrict__ pos2, const float2* __restrict__ prev2,
            const double* __restrict__ partials, const float* __restrict__ el_in,
            float* __restrict__ out) {
    const float4* pos4  = (const float4*)pos2;
    const float4* prev4 = (const float4*)prev2;
    float4* newpos4 = (float4*)(out + NEWPOS_OFF);
    BAND_PROLOGUE

    // Every wave reduces all 1024 partials in identical fixed order (16 coalesced
    // f64 loads + 6-step butterfly) -> bit-identical scale everywhere; no
    // __syncthreads gating, no extra dispatch, deterministic.
    double a = 0.0;
    #pragma unroll
    for (int k = 0; k < NBLK / 64; ++k)
        a += partials[k * 64 + lane];
    #pragma unroll
    for (int m = 1; m < 64; m <<= 1)
        a += __shfl_xor(a, m, 64);
    const float energy = (float)a;
    const float el = el_in[0];
    float en = __fmul_rn(fminf(energy, el), 0.99997f);              // min * DECAY
    en = __fadd_rn(__fmul_rn(en, 0.8f), __fmul_rn(energy, 0.2f));  // pp blend
    const float scale = __fdiv_rn(en, __fadd_rn(energy, 1e-6f));
    if (blockIdx.x == 0 && tid == 0)
        out[ENERGY_OFF] = __fadd_rn(__fmul_rn(el, 0.997f), __fmul_rn(en, 0.003f));

    int prevA = -1, prevB = -1;
    #pragma unroll
    for (int r = 0; r < NR; ++r) {
        ROW_NEIGHBORS(r)
        float da0, da1, db0, db1;
        row_diff(c, P[r], P[r + 2], has_u, has_d, lx, ly, has_l, rx, ry, has_r,
                 pv, maybe_pin, i, jp, da0, da1, db0, db1);

        // vel_dir*vel == diff*scale (exact algebra; <=2ulp vs reference chain,
        // slack is ~4853 global threshold) -> single fma per channel
        const float na0 = __fmaf_rn(da0, scale, c.x);
        const float na1 = __fmaf_rn(da1, scale, c.y);
        const float nb0 = __fmaf_rn(db0, scale, c.z);
        const float nb1 = __fmaf_rn(db1, scale, c.w);
        newpos4[i * PW + pj] = make_float4(na0, na1, nb0, nb1);

        const float xA = __fadd_rn(__fmul_rn(__fmul_rn(na1, 4.8828125e-4f), 784.0f), 10.0f);
        const float yA = __fadd_rn(__fmul_rn(__fmul_rn(na0, 4.8828125e-4f), 104.0f), 690.0f);
        const int pxA = (int)fminf(fmaxf(xA, 0.0f), 803.0f) - 2;
        const int pyA = (int)fminf(fmaxf(yA, 0.0f), 803.0f) - 2;
        int pixA = -1;
        if ((unsigned)pxA < 800u && (unsigned)pyA < 800u) pixA = pyA * 800 + pxA;

        const float xB = __fadd_rn(__fmul_rn(__fmul_rn(nb1, 4.8828125e-4f), 784.0f), 10.0f);
        const float yB = __fadd_rn(__fmul_rn(__fmul_rn(nb0, 4.8828125e-4f), 104.0f), 690.0f);
        const int pxB = (int)fminf(fmaxf(xB, 0.0f), 803.0f) - 2;
        const int pyB = (int)fminf(fmaxf(yB, 0.0f), 803.0f) - 2;
        int pixB = -1;
        if ((unsigned)pxB < 800u && (unsigned)pyB < 800u) pixB = pyB * 800 + pxB;

        // dedup (lossless, stores idempotent): vertical rolling + horizontal shfl
        const int leftB = __shfl_up(pixB, 1);
        const bool dupA = (pixA == prevA) || (lane > 0 && pixA == leftB);
        const bool dupB = (pixB == prevB) || (pixB == pixA);
        if (pixA >= 0 && !dupA) out[pixA * 3 + 1] = 255.0f;
        if (pixB >= 0 && !dupB) out[pixB * 3 + 1] = 255.0f;
        prevA = pixA; prevB = pixB;
    }
}

extern "C" void kernel_launch(void* const* d_in, const int* in_sizes, int n_in,
                              void* d_out, int out_size, void* d_ws, size_t ws_size,
                              hipStream_t stream) {
    const float2* pos  = (const float2*)d_in[0];
    const float2* prev = (const float2*)d_in[1];
    const float*  el   = (const float*)d_in[2];
    float* out = (float*)d_out;
    double* partials = (double*)d_ws;

    hipLaunchKernelGGL(k_energy, dim3(NBLK), dim3(NTHR), 0, stream,
                       pos, prev, out, partials);
    hipLaunchKernelGGL(k_emit, dim3(NBLK), dim3(NTHR), 0, stream,
                       pos, prev, partials, el, out);
}

// Round 11
// 38.911 us; speedup vs baseline: 1.6805x; 1.0065x over previous
//
#include <hip/hip_runtime.h>
#include <hip/hip_cooperative_groups.h>

namespace cg = cooperative_groups;

namespace {
constexpr int H = 2048, W = 2048;
constexpr int PW = W / 2;                     // pair-columns per row
constexpr int CELLS = H * W;
constexpr int FRAME_ELEMS = 800 * 800 * 3;
constexpr int NEWPOS_OFF = FRAME_ELEMS;
constexpr int ENERGY_OFF = FRAME_ELEMS + CELLS * 2;
constexpr int NTHR = 256;
constexpr int NR = 8;                         // rows per band; halo 10/8 = 1.25x
constexpr int BANDS = H / NR;                 // 256
constexpr int CTILES = PW / NTHR;             // 4
constexpr int NBLK = BANDS * CTILES;          // 1024 blocks (= 4/CU if VGPR<=128)
constexpr int NCU = 256;
}

__device__ __forceinline__ void spring(float& f0, float& f1,
                                       float px, float py, float nx, float ny) {
    f0 = __fadd_rn(f0, __fmul_rn(__fsub_rn(px, nx), -4.0f));
    f1 = __fadd_rn(f1, __fmul_rn(__fsub_rn(py, ny), -4.0f));
}

// diff for pair (A,B): exact reference force chain (right,down,left,up + pins).
__device__ __forceinline__ void row_diff(float4 c, float4 up, float4 dn,
                                         bool has_u, bool has_d,
                                         float lx, float ly, bool has_l,
                                         float rx, float ry, bool has_r,
                                         float4 pv, bool maybe_pin, int i, int jp,
                                         float& da0, float& da1,
                                         float& db0, float& db1) {
    float fa0 = -9.8f, fa1 = 0.0f, fb0 = -9.8f, fb1 = 0.0f;
    spring(fa0, fa1, c.x, c.y, c.z, c.w);                  // A right = B
    if (has_r) spring(fb0, fb1, c.z, c.w, rx, ry);         // B right
    if (has_d) { spring(fa0, fa1, c.x, c.y, dn.x, dn.y);   // A down
                 spring(fb0, fb1, c.z, c.w, dn.z, dn.w); } // B down
    if (has_l) spring(fa0, fa1, c.x, c.y, lx, ly);         // A left
    spring(fb0, fb1, c.z, c.w, c.x, c.y);                  // B left = A
    if (has_u) { spring(fa0, fa1, c.x, c.y, up.x, up.y);   // A up
                 spring(fb0, fb1, c.z, c.w, up.z, up.w); } // B up
    if (maybe_pin) {
        const int jb = jp + 1;
        const bool pinA = ((i == H - 1) && (jp < W / 2) && (jp % 9 == 0)) ||
                          ((i == 0) && (jp % 9 == 0));
        const bool pinB = ((i == H - 1) && (jb < W / 2) && (jb % 9 == 0)) ||
                          ((i == 0) && (jb % 9 == 0));
        if (pinA) { fa0 = 0.0f; fa1 = 0.0f; }
        if (pinB) { fb0 = 0.0f; fb1 = 0.0f; }
    }
    da0 = __fsub_rn(__fadd_rn(__fsub_rn(__fmul_rn(2.0f, c.x), pv.x), fa0), c.x);
    da1 = __fsub_rn(__fadd_rn(__fsub_rn(__fmul_rn(2.0f, c.y), pv.y), fa1), c.y);
    db0 = __fsub_rn(__fadd_rn(__fsub_rn(__fmul_rn(2.0f, c.z), pv.z), fb0), c.z);
    db1 = __fsub_rn(__fadd_rn(__fsub_rn(__fmul_rn(2.0f, c.w), pv.w), fb1), c.w);
}

#define BAND_PROLOGUE                                                          \
    const int tid  = threadIdx.x;                                              \
    const int lane = tid & 63;                                                 \
    const int band = blockIdx.x >> 2;                                          \
    const int ct   = blockIdx.x & 3;                                           \
    const int i0   = band * NR;                                                \
    const int pj   = ct * NTHR + tid;                                          \
    const int jp   = pj << 1;                                                  \
    float4 P[NR + 2];                                                          \
    _Pragma("unroll")                                                          \
    for (int r = 0; r < NR + 2; ++r) {                                         \
        const int row = i0 - 1 + r;                                            \
        P[r] = (row >= 0 && row < H) ? pos4[row * PW + pj]                     \
                                     : make_float4(0.f, 0.f, 0.f, 0.f);        \
    }

#define ROW_NEIGHBORS(r)                                                       \
    const int i = i0 + (r);                                                    \
    const float4 c = P[(r) + 1];                                               \
    const bool has_u = !((r) == 0 && band == 0);                               \
    const bool has_d = !((r) == NR - 1 && band == BANDS - 1);                  \
    const bool has_l = (jp > 0), has_r = (jp + 2 < W);                         \
    float lx = __shfl_up(c.z, 1), ly = __shfl_up(c.w, 1);                      \
    if (lane == 0 && has_l) {                                                  \
        const float2 t = pos2[i * W + jp - 1]; lx = t.x; ly = t.y;             \
    }                                                                          \
    float rx = __shfl_down(c.x, 1), ry = __shfl_down(c.y, 1);                  \
    if (lane == 63 && has_r) {                                                 \
        const float2 t = pos2[i * W + jp + 2]; rx = t.x; ry = t.y;             \
    }                                                                          \
    const float4 pv = prev4[i * PW + pj];                                      \
    const bool maybe_pin = ((r) == 0 && band == 0) ||                          \
                           ((r) == NR - 1 && band == BANDS - 1);

// raster one row-pair with vertical+horizontal dedup (lossless; stores idempotent)
__device__ __forceinline__ void raster_pair(float na0, float na1, float nb0, float nb1,
                                            int lane, int& prevA, int& prevB,
                                            float* __restrict__ out) {
    const float xA = __fadd_rn(__fmul_rn(__fmul_rn(na1, 4.8828125e-4f), 784.0f), 10.0f);
    const float yA = __fadd_rn(__fmul_rn(__fmul_rn(na0, 4.8828125e-4f), 104.0f), 690.0f);
    const int pxA = (int)fminf(fmaxf(xA, 0.0f), 803.0f) - 2;
    const int pyA = (int)fminf(fmaxf(yA, 0.0f), 803.0f) - 2;
    int pixA = -1;
    if ((unsigned)pxA < 800u && (unsigned)pyA < 800u) pixA = pyA * 800 + pxA;
    const float xB = __fadd_rn(__fmul_rn(__fmul_rn(nb1, 4.8828125e-4f), 784.0f), 10.0f);
    const float yB = __fadd_rn(__fmul_rn(__fmul_rn(nb0, 4.8828125e-4f), 104.0f), 690.0f);
    const int pxB = (int)fminf(fmaxf(xB, 0.0f), 803.0f) - 2;
    const int pyB = (int)fminf(fmaxf(yB, 0.0f), 803.0f) - 2;
    int pixB = -1;
    if ((unsigned)pxB < 800u && (unsigned)pyB < 800u) pixB = pyB * 800 + pxB;
    const int leftB = __shfl_up(pixB, 1);
    const bool dupA = (pixA == prevA) || (lane > 0 && pixA == leftB);
    const bool dupB = (pixB == prevB) || (pixB == pixA);
    if (pixA >= 0 && !dupA) out[pixA * 3 + 1] = 255.0f;
    if (pixB >= 0 && !dupB) out[pixB * 3 + 1] = 255.0f;
    prevA = pixA; prevB = pixB;
}

// =================== PATH 1: fused cooperative (1 dispatch) ===================
__global__ __launch_bounds__(NTHR, 4)
void k_fused(const float2* __restrict__ pos2, const float2* __restrict__ prev2,
             const float* __restrict__ el_in, float* __restrict__ out,
             double* __restrict__ partials) {
    const float4* pos4  = (const float4*)pos2;
    const float4* prev4 = (const float4*)prev2;
    float4* frame4  = (float4*)out;
    float4* newpos4 = (float4*)(out + NEWPOS_OFF);

    {   // zero the frame before the grid sync (R2-validated visibility)
        const int g = blockIdx.x * NTHR + threadIdx.x;
        for (int k = g; k < FRAME_ELEMS / 4; k += NBLK * NTHR)
            frame4[k] = make_float4(0.f, 0.f, 0.f, 0.f);
    }
    BAND_PROLOGUE

    // persistent across sync: diff (32 VGPR) + center pos (32 VGPR)
    float d0[NR], d1[NR], d2[NR], d3[NR];
    float4 C[NR];
    double acc = 0.0;
    #pragma unroll
    for (int r = 0; r < NR; ++r) {
        ROW_NEIGHBORS(r)
        row_diff(c, P[r], P[r + 2], has_u, has_d, lx, ly, has_l, rx, ry, has_r,
                 pv, maybe_pin, i, jp, d0[r], d1[r], d2[r], d3[r]);
        C[r] = c;
        acc += (double)__fadd_rn(__fmul_rn(d0[r], d0[r]), __fmul_rn(d1[r], d1[r]));
        acc += (double)__fadd_rn(__fmul_rn(d2[r], d2[r]), __fmul_rn(d3[r], d3[r]));
    }
    {
        __shared__ double sm[NTHR];
        sm[tid] = acc;
        __syncthreads();
        for (int s = NTHR / 2; s > 0; s >>= 1) {
            if (tid < s) sm[tid] += sm[tid + s];
            __syncthreads();
        }
        if (tid == 0) partials[blockIdx.x] = sm[0];
    }
    __threadfence();
    cg::this_grid().sync();

    // wave-redundant fixed-order reduce -> bit-identical scale (R9-validated)
    double a = 0.0;
    #pragma unroll
    for (int k = 0; k < NBLK / 64; ++k)
        a += partials[k * 64 + lane];
    #pragma unroll
    for (int m = 1; m < 64; m <<= 1)
        a += __shfl_xor(a, m, 64);
    const float energy = (float)a;
    const float el = el_in[0];
    float en = __fmul_rn(fminf(energy, el), 0.99997f);
    en = __fadd_rn(__fmul_rn(en, 0.8f), __fmul_rn(energy, 0.2f));
    const float scale = __fdiv_rn(en, __fadd_rn(energy, 1e-6f));
    if (blockIdx.x == 0 && tid == 0)
        out[ENERGY_OFF] = __fadd_rn(__fmul_rn(el, 0.997f), __fmul_rn(en, 0.003f));

    int prevA = -1, prevB = -1;
    #pragma unroll
    for (int r = 0; r < NR; ++r) {
        const int i = i0 + r;
        const float na0 = __fmaf_rn(d0[r], scale, C[r].x);
        const float na1 = __fmaf_rn(d1[r], scale, C[r].y);
        const float nb0 = __fmaf_rn(d2[r], scale, C[r].z);
        const float nb1 = __fmaf_rn(d3[r], scale, C[r].w);
        newpos4[i * PW + pj] = make_float4(na0, na1, nb0, nb1);
        raster_pair(na0, na1, nb0, nb1, lane, prevA, prevB, out);
    }
}

// =================== PATH 2: R9 fallback (2 dispatches, validated) ===================
__global__ __launch_bounds__(NTHR)
void k_energy(const float2* __restrict__ pos2, const float2* __restrict__ prev2,
              float* __restrict__ out, double* __restrict__ partials) {
    const float4* pos4  = (const float4*)pos2;
    const float4* prev4 = (const float4*)prev2;
    float4* frame4 = (float4*)out;
    {
        const int g = blockIdx.x * NTHR + threadIdx.x;
        for (int k = g; k < FRAME_ELEMS / 4; k += NBLK * NTHR)
            frame4[k] = make_float4(0.f, 0.f, 0.f, 0.f);
    }
    BAND_PROLOGUE
    double acc = 0.0;
    #pragma unroll
    for (int r = 0; r < NR; ++r) {
        ROW_NEIGHBORS(r)
        float da0, da1, db0, db1;
        row_diff(c, P[r], P[r + 2], has_u, has_d, lx, ly, has_l, rx, ry, has_r,
                 pv, maybe_pin, i, jp, da0, da1, db0, db1);
        acc += (double)__fadd_rn(__fmul_rn(da0, da0), __fmul_rn(da1, da1));
        acc += (double)__fadd_rn(__fmul_rn(db0, db0), __fmul_rn(db1, db1));
    }
    __shared__ double sm[NTHR];
    sm[tid] = acc;
    __syncthreads();
    for (int s = NTHR / 2; s > 0; s >>= 1) {
        if (tid < s) sm[tid] += sm[tid + s];
        __syncthreads();
    }
    if (tid == 0) partials[blockIdx.x] = sm[0];
}

__global__ __launch_bounds__(NTHR)
void k_emit(const float2* __restrict__ pos2, const float2* __restrict__ prev2,
            const double* __restrict__ partials, const float* __restrict__ el_in,
            float* __restrict__ out) {
    const float4* pos4  = (const float4*)pos2;
    const float4* prev4 = (const float4*)prev2;
    float4* newpos4 = (float4*)(out + NEWPOS_OFF);
    BAND_PROLOGUE
    double a = 0.0;
    #pragma unroll
    for (int k = 0; k < NBLK / 64; ++k)
        a += partials[k * 64 + lane];
    #pragma unroll
    for (int m = 1; m < 64; m <<= 1)
        a += __shfl_xor(a, m, 64);
    const float energy = (float)a;
    const float el = el_in[0];
    float en = __fmul_rn(fminf(energy, el), 0.99997f);
    en = __fadd_rn(__fmul_rn(en, 0.8f), __fmul_rn(energy, 0.2f));
    const float scale = __fdiv_rn(en, __fadd_rn(energy, 1e-6f));
    if (blockIdx.x == 0 && tid == 0)
        out[ENERGY_OFF] = __fadd_rn(__fmul_rn(el, 0.997f), __fmul_rn(en, 0.003f));

    int prevA = -1, prevB = -1;
    #pragma unroll
    for (int r = 0; r < NR; ++r) {
        ROW_NEIGHBORS(r)
        float da0, da1, db0, db1;
        row_diff(c, P[r], P[r + 2], has_u, has_d, lx, ly, has_l, rx, ry, has_r,
                 pv, maybe_pin, i, jp, da0, da1, db0, db1);
        const float na0 = __fmaf_rn(da0, scale, c.x);
        const float na1 = __fmaf_rn(da1, scale, c.y);
        const float nb0 = __fmaf_rn(db0, scale, c.z);
        const float nb1 = __fmaf_rn(db1, scale, c.w);
        newpos4[i * PW + pj] = make_float4(na0, na1, nb0, nb1);
        raster_pair(na0, na1, nb0, nb1, lane, prevA, prevB, out);
    }
}

extern "C" void kernel_launch(void* const* d_in, const int* in_sizes, int n_in,
                              void* d_out, int out_size, void* d_ws, size_t ws_size,
                              hipStream_t stream) {
    const float2* pos  = (const float2*)d_in[0];
    const float2* prev = (const float2*)d_in[1];
    const float*  el   = (const float*)d_in[2];
    float* out = (float*)d_out;
    double* partials = (double*)d_ws;

    // Capture-safe host-side occupancy gate (deterministic per binary):
    // cooperative launch is a runtime co-residency contract — verify it first.
    int maxb = 0;
    hipError_t qerr = hipOccupancyMaxActiveBlocksPerMultiprocessor(
        &maxb, (const void*)k_fused, NTHR, 0);
    bool coop = (qerr == hipSuccess) && (maxb * NCU >= NBLK);

    if (coop) {
        void* args[] = { (void*)&pos, (void*)&prev, (void*)&el,
                         (void*)&out, (void*)&partials };
        hipError_t lerr = hipLaunchCooperativeKernel((void*)k_fused, dim3(NBLK),
                                                     dim3(NTHR), args, 0, stream);
        if (lerr == hipSuccess) return;     // fused path engaged
    }
    // validated R9 fallback
    hipLaunchKernelGGL(k_energy, dim3(NBLK), dim3(NTHR), 0, stream,
                       pos, prev, out, partials);
    hipLaunchKernelGGL(k_emit, dim3(NBLK), dim3(NTHR), 0, stream,
                       pos, prev, partials, el, out);
}